// Round 2
// baseline (5052.925 us; speedup 1.0000x reference)
//
#include <hip/hip_runtime.h>
#include <cstddef>

#define LOG2E 1.4426950408889634f
#define LN2   0.6931471805599453f

constexpr int K_    = 256;
constexpr int T_    = 2048;
constexpr int DMAX_ = 64;
constexpr int B_    = 16;

// 512 threads = 8 waves. tid = (q<<8) | j ; j = column (state), q = i-half.
// Per thread: P_reg[128] = exp(A[i][j]) for i in [128q,128q+128)  (128 VGPRs)
//             pD[32]     = exp(D[j][d]) for ages 32q+1 .. 32q+32
//             v[32]      = linear duration buffer (column-anchored)
__global__ __launch_bounds__(512, 2)
void hsmm_fwd_kernel(const float* __restrict__ logB,   // [B,T,K]
                     const float* __restrict__ pi,     // [K]
                     const float* __restrict__ A,      // [K,K]
                     const float* __restrict__ D,      // [K,DMAX]
                     float* __restrict__ out)          // [16] loglik ++ [B,T,K] alphas
{
    const int b   = blockIdx.x;
    const int tid = threadIdx.x;
    const int j   = tid & 255;
    const int q   = tid >> 8;      // 0 or 1

    __shared__ float lds_Sdur[2][K_];
    __shared__ float lds_Smv[2][K_];
    alignas(16) __shared__ float lds_p[K_];
    __shared__ float lds_hand[2][K_];   // ping-pong by t&1
    __shared__ float lds_red[8];

    // ---- init: transition probs (linear), duration probs (linear) ----
    float P_reg[128];
    {
        const float* Abase = A + (size_t)(128 * q) * K_ + j;
        #pragma unroll
        for (int i = 0; i < 128; ++i)
            P_reg[i] = exp2f(Abase[(size_t)i * K_] * LOG2E);   // diag -1e30 -> 0
    }
    float pD[32];
    {
        const float* Dbase = D + (size_t)j * DMAX_ + 32 * q;
        #pragma unroll
        for (int a = 0; a < 32; ++a)
            pD[a] = exp2f(Dbase[a] * LOG2E);
    }

    float v[32];
    #pragma unroll
    for (int a = 0; a < 32; ++a) v[a] = 0.0f;
    if (q == 0) v[0] = 1.0f;            // age-1 slot holds pi (anchor = pi2)
    float mcol     = pi[j] * LOG2E;     // column anchor (base-2)
    float cumb     = 0.0f;              // running cumsum of logB (base-2)
    float m_anchor = 0.0f;              // global anchor for p (lagged max)
    float m_loglik = 0.0f;
    float r_prev   = 1.0f;

    if (q == 0) { lds_hand[0][j] = 0.0f; lds_hand[1][j] = 0.0f; }
    __syncthreads();

    const float* logB_b    = logB + (size_t)b * T_ * K_;
    float*       alphas_out = out + 16 + (size_t)b * T_ * K_;
    float bload = logB_b[j];            // t = 0 emission

    for (int t = 0; t < T_; ++t) {
        // ---- P1: emission cumsum; q1 consumes last step's boundary handoff ----
        cumb += bload * LOG2E;
        if (q == 1) v[0] = lds_hand[(t & 1) ^ 1][j] * r_prev;  // age-33 arrives

        // ---- P2: duration partial sums  S_q = sum_a v[a]*pD[a] ----
        float s0 = 0.f, s1 = 0.f, s2 = 0.f, s3 = 0.f;
        #pragma unroll
        for (int a = 0; a < 32; a += 4) {
            s0 = fmaf(v[a + 0], pD[a + 0], s0);
            s1 = fmaf(v[a + 1], pD[a + 1], s1);
            s2 = fmaf(v[a + 2], pD[a + 2], s2);
            s3 = fmaf(v[a + 3], pD[a + 3], s3);
        }
        lds_Sdur[q][j] = (s0 + s1) + (s2 + s3);
        if (q == 0) lds_hand[t & 1][j] = v[31];   // pre-shift age-32 -> next step's age-33
        __syncthreads();  // B1

        // ---- P3: alpha, p, lagged-max reduce ----
        float S      = lds_Sdur[0][j] + lds_Sdur[1][j];
        float alpha2 = cumb + mcol + log2f(S);
        float p_j    = exp2f(alpha2 - m_anchor);
        if (q == 0) {
            lds_p[j] = p_j;
            alphas_out[(size_t)t * K_ + j] = alpha2 * LN2;
        }
        float wm = alpha2;
        #pragma unroll
        for (int off = 1; off < 64; off <<= 1)
            wm = fmaxf(wm, __shfl_xor(wm, off, 64));
        if ((tid & 63) == 0) lds_red[tid >> 6] = wm;
        m_loglik = m_anchor;
        __syncthreads();  // B2

        // ---- P4: matvec  Smv_q = sum_{i in half} p[i] * P[i][j] ----
        const float4* p4 = (const float4*)lds_p + 32 * q;
        float a0 = 0.f, a1 = 0.f, a2 = 0.f, a3 = 0.f;
        #pragma unroll
        for (int g = 0; g < 32; ++g) {
            float4 pv = p4[g];
            a0 = fmaf(pv.x, P_reg[4 * g + 0], a0);
            a1 = fmaf(pv.y, P_reg[4 * g + 1], a1);
            a2 = fmaf(pv.z, P_reg[4 * g + 2], a2);
            a3 = fmaf(pv.w, P_reg[4 * g + 3], a3);
        }
        lds_Smv[q][j] = (a0 + a1) + (a2 + a3);
        float m_next = fmaxf(
            fmaxf(fmaxf(lds_red[0], lds_red[1]), fmaxf(lds_red[2], lds_red[3])),
            fmaxf(fmaxf(lds_red[4], lds_red[5]), fmaxf(lds_red[6], lds_red[7])));
        if (t + 1 < T_) bload = logB_b[(size_t)(t + 1) * K_ + j];  // prefetch
        __syncthreads();  // B3

        // ---- P5: a_in, anchor update, fused shift+rescale insert ----
        float Smv   = lds_Smv[0][j] + lds_Smv[1][j];
        float a_in2 = m_anchor + log2f(Smv);
        float v2new = a_in2 - cumb;
        float r, newval;
        if (v2new > mcol) {
            r = exp2f(mcol - v2new); newval = 1.0f; mcol = v2new;
        } else {
            r = 1.0f; newval = exp2f(v2new - mcol);
        }
        #pragma unroll
        for (int a = 31; a >= 1; --a) v[a] = v[a - 1] * r;  // age++ & rescale
        if (q == 0) v[0] = newval;       // q1's v[0] refilled next P1 from handoff
        r_prev   = r;
        m_anchor = m_next;
    }

    // ---- loglik: lds_p holds exp2(alpha_last - m_loglik), stable since B2/B3 ----
    if (tid < 64) {
        float s = lds_p[tid] + lds_p[tid + 64] + lds_p[tid + 128] + lds_p[tid + 192];
        #pragma unroll
        for (int off = 1; off < 64; off <<= 1)
            s += __shfl_xor(s, off, 64);
        if (tid == 0) out[b] = (m_loglik + log2f(s)) * LN2;
    }
}

extern "C" void kernel_launch(void* const* d_in, const int* in_sizes, int n_in,
                              void* d_out, int out_size, void* d_ws, size_t ws_size,
                              hipStream_t stream) {
    const float* logB = (const float*)d_in[0];   // [16,2048,256]
    const float* pi   = (const float*)d_in[1];   // [256]
    const float* A    = (const float*)d_in[2];   // [256,256]
    const float* D    = (const float*)d_in[3];   // [256,64]
    float* out = (float*)d_out;
    (void)in_sizes; (void)n_in; (void)d_ws; (void)ws_size; (void)out_size;

    hipLaunchKernelGGL(hsmm_fwd_kernel, dim3(B_), dim3(512), 0, stream,
                       logB, pi, A, D, out);
}

// Round 3
// 3289.234 us; speedup vs baseline: 1.5362x; 1.5362x over previous
//
#include <hip/hip_runtime.h>
#include <cstddef>

#define LOG2E 1.4426950408889634f
#define LN2   0.6931471805599453f

typedef float f32x2 __attribute__((ext_vector_type(2)));
typedef float f32x4 __attribute__((ext_vector_type(4)));

constexpr int K_    = 256;
constexpr int T_    = 2048;
constexpr int DMAX_ = 64;
constexpr int B_    = 16;

__device__ __forceinline__ float fexp2(float x) { return __builtin_amdgcn_exp2f(x); }
__device__ __forceinline__ float flog2(float x) { return __builtin_amdgcn_logf(x); }

// 512 threads = 8 waves. tid = (q<<8) | j ; j = column (state), q = i-half.
// Per thread: P2[64]  = exp(A[i][j]) packed f32x2, i in [128q,128q+128)  (128 VGPRs)
//             pD2[16] = exp(D[j][d]) packed, ages 32q+1 .. 32q+32
//             v2[16]  = linear duration buffer (column-anchored), packed
__global__ __launch_bounds__(512, 2)
void hsmm_fwd_kernel(const float* __restrict__ logB,   // [B,T,K]
                     const float* __restrict__ pi,     // [K]
                     const float* __restrict__ A,      // [K,K]
                     const float* __restrict__ D,      // [K,DMAX]
                     float* __restrict__ out)          // [16] loglik ++ [B,T,K] alphas
{
    const int b   = blockIdx.x;
    const int tid = threadIdx.x;
    const int j   = tid & 255;
    const int q   = tid >> 8;      // 0 or 1

    __shared__ float lds_Sdur[2][K_];
    __shared__ float lds_Smv[2][K_];
    alignas(16) __shared__ float lds_p[K_];
    __shared__ float lds_hand[2][K_];   // ping-pong by t&1
    __shared__ float lds_red[8];

    // ---- init: transition probs (linear, packed), duration probs (linear) ----
    f32x2 P2[64];
    {
        const float* Abase = A + (size_t)(128 * q) * K_ + j;
        #pragma unroll
        for (int k = 0; k < 64; ++k) {
            P2[k].x = fexp2(Abase[(size_t)(2 * k + 0) * K_] * LOG2E);
            P2[k].y = fexp2(Abase[(size_t)(2 * k + 1) * K_] * LOG2E);
        }
    }
    f32x2 pD2[16];
    {
        const float* Dbase = D + (size_t)j * DMAX_ + 32 * q;
        #pragma unroll
        for (int k = 0; k < 16; ++k) {
            pD2[k].x = fexp2(Dbase[2 * k + 0] * LOG2E);
            pD2[k].y = fexp2(Dbase[2 * k + 1] * LOG2E);
        }
    }

    f32x2 v2[16];
    #pragma unroll
    for (int k = 0; k < 16; ++k) { v2[k].x = 0.0f; v2[k].y = 0.0f; }
    if (q == 0) v2[0].x = 1.0f;         // age-1 slot holds pi (anchor = pi2)
    float mcol     = pi[j] * LOG2E;     // column anchor (base-2)
    float cumb     = 0.0f;              // running cumsum of logB (base-2)
    float m_anchor = 0.0f;              // global anchor for p (lagged max)
    float m_loglik = 0.0f;
    float r_prev   = 1.0f;

    if (q == 0) { lds_hand[0][j] = 0.0f; lds_hand[1][j] = 0.0f; }
    __syncthreads();

    const float* logB_b     = logB + (size_t)b * T_ * K_;
    float*       alphas_out = out + 16 + (size_t)b * T_ * K_;
    float bload = logB_b[j];            // t = 0 emission

    for (int t = 0; t < T_; ++t) {
        // ---- P1: emission cumsum; q1 consumes last step's boundary handoff ----
        cumb += bload * LOG2E;
        if (q == 1) v2[0].x = lds_hand[(t & 1) ^ 1][j] * r_prev;  // age-33 arrives

        // ---- P2: duration partial sums  S_q = sum_a v[a]*pD[a]  (packed) ----
        f32x2 s0 = {0.f, 0.f}, s1 = {0.f, 0.f};
        #pragma unroll
        for (int k = 0; k < 16; k += 2) {
            asm("v_pk_fma_f32 %0, %1, %2, %0" : "+v"(s0) : "v"(v2[k + 0]), "v"(pD2[k + 0]));
            asm("v_pk_fma_f32 %0, %1, %2, %0" : "+v"(s1) : "v"(v2[k + 1]), "v"(pD2[k + 1]));
        }
        lds_Sdur[q][j] = (s0.x + s0.y) + (s1.x + s1.y);
        if (q == 0) lds_hand[t & 1][j] = v2[15].y;  // pre-shift age-32 -> next step's age-33
        __syncthreads();  // B1

        // ---- P3: alpha, p, lagged-max reduce ----
        float S      = lds_Sdur[0][j] + lds_Sdur[1][j];
        float alpha2 = cumb + mcol + flog2(S);
        float p_j    = fexp2(alpha2 - m_anchor);
        if (q == 0) {
            lds_p[j] = p_j;
            alphas_out[(size_t)t * K_ + j] = alpha2 * LN2;
        }
        float wm = alpha2;
        #pragma unroll
        for (int off = 1; off < 64; off <<= 1)
            wm = fmaxf(wm, __shfl_xor(wm, off, 64));
        if ((tid & 63) == 0) lds_red[tid >> 6] = wm;
        m_loglik = m_anchor;
        __syncthreads();  // B2

        // ---- P4: matvec  Smv_q = sum_{i in half} p[i] * P[i][j]  (packed) ----
        const f32x4* p4 = (const f32x4*)lds_p + 32 * q;
        f32x2 a0 = {0.f, 0.f}, a1 = {0.f, 0.f}, a2 = {0.f, 0.f}, a3 = {0.f, 0.f};
        #pragma unroll
        for (int g = 0; g < 32; g += 2) {
            f32x4 pv0 = p4[g];
            f32x4 pv1 = p4[g + 1];
            f32x2 pv0lo = pv0.lo, pv0hi = pv0.hi, pv1lo = pv1.lo, pv1hi = pv1.hi;
            asm("v_pk_fma_f32 %0, %1, %2, %0" : "+v"(a0) : "v"(pv0lo), "v"(P2[2 * g + 0]));
            asm("v_pk_fma_f32 %0, %1, %2, %0" : "+v"(a1) : "v"(pv0hi), "v"(P2[2 * g + 1]));
            asm("v_pk_fma_f32 %0, %1, %2, %0" : "+v"(a2) : "v"(pv1lo), "v"(P2[2 * g + 2]));
            asm("v_pk_fma_f32 %0, %1, %2, %0" : "+v"(a3) : "v"(pv1hi), "v"(P2[2 * g + 3]));
        }
        lds_Smv[q][j] = ((a0.x + a0.y) + (a1.x + a1.y)) + ((a2.x + a2.y) + (a3.x + a3.y));
        float m_next = fmaxf(
            fmaxf(fmaxf(lds_red[0], lds_red[1]), fmaxf(lds_red[2], lds_red[3])),
            fmaxf(fmaxf(lds_red[4], lds_red[5]), fmaxf(lds_red[6], lds_red[7])));
        if (t + 1 < T_) bload = logB_b[(size_t)(t + 1) * K_ + j];  // prefetch
        __syncthreads();  // B3

        // ---- P5: a_in, anchor update, fused shift+rescale insert ----
        float Smv   = lds_Smv[0][j] + lds_Smv[1][j];
        float a_in2 = m_anchor + flog2(Smv);
        float v2new = a_in2 - cumb;
        float r, newval;
        if (v2new > mcol) {
            r = fexp2(mcol - v2new); newval = 1.0f; mcol = v2new;
        } else {
            r = 1.0f; newval = fexp2(v2new - mcol);
        }
        // age++ & rescale (descending, component-wise through packed pairs)
        #pragma unroll
        for (int k = 15; k >= 1; --k) {
            v2[k].y = v2[k].x * r;
            v2[k].x = v2[k - 1].y * r;
        }
        v2[0].y = v2[0].x * r;
        if (q == 0) v2[0].x = newval;    // q1's v2[0].x refilled next P1 from handoff
        else        v2[0].x = 0.0f;      // placeholder until handoff arrives
        r_prev   = r;
        m_anchor = m_next;
    }

    // ---- loglik: lds_p holds exp2(alpha_last - m_loglik), stable since B2/B3 ----
    if (tid < 64) {
        float s = lds_p[tid] + lds_p[tid + 64] + lds_p[tid + 128] + lds_p[tid + 192];
        #pragma unroll
        for (int off = 1; off < 64; off <<= 1)
            s += __shfl_xor(s, off, 64);
        if (tid == 0) out[b] = (m_loglik + flog2(s)) * LN2;
    }
}

extern "C" void kernel_launch(void* const* d_in, const int* in_sizes, int n_in,
                              void* d_out, int out_size, void* d_ws, size_t ws_size,
                              hipStream_t stream) {
    const float* logB = (const float*)d_in[0];   // [16,2048,256]
    const float* pi   = (const float*)d_in[1];   // [256]
    const float* A    = (const float*)d_in[2];   // [256,256]
    const float* D    = (const float*)d_in[3];   // [256,64]
    float* out = (float*)d_out;
    (void)in_sizes; (void)n_in; (void)d_ws; (void)ws_size; (void)out_size;

    hipLaunchKernelGGL(hsmm_fwd_kernel, dim3(B_), dim3(512), 0, stream,
                       logB, pi, A, D, out);
}